// Round 12
// baseline (3557.051 us; speedup 1.0000x reference)
//
#include <hip/hip_runtime.h>

#define NN 100000
#define EE 3200000
#define FIN 128
#define HID 16
#define NC 8

#define CHUNK 12500
#define NBLK 256                           // CHUNK*NBLK == EE exactly
#define BW 256                             // nodes per bucket
#define NBUK ((NN + BW - 1) / BW)          // 391
#define EPT 13                             // ceil(CHUNK/1024)
#define CAP 9216                           // bucket slab capacity (mean 8184, sigma 90 -> 11 sigma)
#define LCH1 2048                          // l1 edge-stage capacity (block mean 1024, sd 32)
#define LCH2 3072                          // l2 edge-stage capacity (block mean 2096, sd 46)

// pack two floats into bf16x2 (round-to-nearest-even)
__device__ __forceinline__ unsigned bf16pair(float a, float b) {
    unsigned ua = __float_as_uint(a), ub = __float_as_uint(b);
    ua = ua + 0x7fffu + ((ua >> 16) & 1u);
    ub = ub + 0x7fffu + ((ub >> 16) & 1u);
    return (ua >> 16) | (ub & 0xffff0000u);
}

// ---------------- pass 1: LDS chunk sort + ticket slab allocation + coalesced writeout ----
// bins_pk[slot] = src | (dst & 255) << 17   (src < 2^17, dl < 2^8)
__global__ __launch_bounds__(1024) void k_binscatter(const int* __restrict__ row,
                                                     const int* __restrict__ col,
                                                     unsigned* __restrict__ cursor,
                                                     unsigned* __restrict__ bins_pk) {
    __shared__ unsigned s_cnt[NBUK];     // raw counts -> (after scan) inclusive
    __shared__ unsigned s_off[NBUK];     // running rank (starts at exclusive start)
    __shared__ unsigned s_gb[NBUK];      // ticket -> folded dest bias (b*CAP + gb - start)
    __shared__ unsigned stg[CHUNK];                 // 50 KB
    __shared__ unsigned short bktid[CHUNK];         // 25 KB
    int t = threadIdx.x;
    for (int i = t; i < NBUK; i += 1024) s_cnt[i] = 0u;
    __syncthreads();
    int base = blockIdx.x * CHUNK;
    unsigned val[EPT];
    unsigned short bk[EPT];
    #pragma unroll
    for (int k = 0; k < EPT; ++k) {
        int i = t + k * 1024;
        if (i < CHUNK) {
            int s = row[base + i];
            int d = col[base + i];
            unsigned b = (unsigned)d >> 8;
            val[k] = (unsigned)s | ((unsigned)(d & 255) << 17);
            bk[k] = (unsigned short)b;
            atomicAdd(&s_cnt[b], 1u);
        }
    }
    __syncthreads();
    // ticket: reserve a contiguous run in each bucket's slab (s_cnt still raw)
    for (int i = t; i < NBUK; i += 1024)
        s_gb[i] = atomicAdd(&cursor[i], s_cnt[i]);
    __syncthreads();
    // inclusive scan s_cnt over NBUK entries
    for (int off = 1; off < NBUK; off <<= 1) {
        unsigned v = 0u;
        if (t < NBUK && t >= off) v = s_cnt[t - off];
        __syncthreads();
        if (t < NBUK) s_cnt[t] += v;
        __syncthreads();
    }
    if (t < NBUK) {
        unsigned st = (t == 0) ? 0u : s_cnt[t - 1];
        s_off[t] = st;
        s_gb[t] = (unsigned)t * CAP + s_gb[t] - st;   // folded dest bias
    }
    __syncthreads();
    // rank-scatter into LDS stage
    #pragma unroll
    for (int k = 0; k < EPT; ++k) {
        int i = t + k * 1024;
        if (i < CHUNK) {
            unsigned b = bk[k];
            unsigned r = atomicAdd(&s_off[b], 1u);
            stg[r] = val[k];
            bktid[r] = (unsigned short)b;
        }
    }
    __syncthreads();
    // coalesced writeout into bucket slabs
    for (int i = t; i < CHUNK; i += 1024) {
        unsigned b = bktid[i];
        bins_pk[s_gb[b] + (unsigned)i] = stg[i];
    }
}

// ---------------- pass 2: per-bucket CSR build (uint4 slab IO, LDS stage) ----------------
__global__ __launch_bounds__(1024) void k_build(const unsigned* __restrict__ bins_pk,
                                                const unsigned* __restrict__ cursor,
                                                uint2* __restrict__ row_se,
                                                float* __restrict__ dinv,
                                                unsigned* __restrict__ srcsort) {
    __shared__ unsigned cnt[BW];       // per-node count -> inclusive scan
    __shared__ unsigned offn[BW];      // running rank
    __shared__ unsigned stg[CAP];      // 36 KB
    int t = threadIdx.x, b = blockIdx.x;
    if (t < BW) cnt[t] = 0u;
    __syncthreads();
    unsigned m = cursor[b];
    unsigned base = (unsigned)b * CAP;
    uint4 w4[3];                       // 3*1024*4 = 12288 covers CAP
    #pragma unroll
    for (int k = 0; k < 3; ++k) {
        unsigned i = (unsigned)(t + k * 1024) * 4u;
        if (i < m) {
            w4[k] = *reinterpret_cast<const uint4*>(&bins_pk[base + i]);
            atomicAdd(&cnt[w4[k].x >> 17], 1u);
            if (i + 1 < m) atomicAdd(&cnt[w4[k].y >> 17], 1u);
            if (i + 2 < m) atomicAdd(&cnt[w4[k].z >> 17], 1u);
            if (i + 3 < m) atomicAdd(&cnt[w4[k].w >> 17], 1u);
        }
    }
    __syncthreads();
    // inclusive scan over BW entries
    for (int off = 1; off < BW; off <<= 1) {
        unsigned v = 0u;
        if (t < BW && t >= off) v = cnt[t - off];
        __syncthreads();
        if (t < BW) cnt[t] += v;
        __syncthreads();
    }
    if (t < BW) {
        unsigned st = (t == 0) ? 0u : cnt[t - 1];
        offn[t] = st;
        int node = b * BW + t;
        if (node < NN) {
            row_se[node] = uint2{base + st, base + cnt[t]};
            dinv[node] = rsqrtf(1.0f + (float)(cnt[t] - st));
        }
    }
    __syncthreads();
    // rank-scatter into LDS stage (in-bucket final order)
    #pragma unroll
    for (int k = 0; k < 3; ++k) {
        unsigned i = (unsigned)(t + k * 1024) * 4u;
        if (i < m) {
            unsigned r;
            r = atomicAdd(&offn[w4[k].x >> 17], 1u); stg[r] = w4[k].x & 0x1FFFFu;
            if (i + 1 < m) { r = atomicAdd(&offn[w4[k].y >> 17], 1u); stg[r] = w4[k].y & 0x1FFFFu; }
            if (i + 2 < m) { r = atomicAdd(&offn[w4[k].z >> 17], 1u); stg[r] = w4[k].z & 0x1FFFFu; }
            if (i + 3 < m) { r = atomicAdd(&offn[w4[k].w >> 17], 1u); stg[r] = w4[k].w & 0x1FFFFu; }
        }
    }
    __syncthreads();
    // sequential uint4 writeout (pad words land in never-read slab padding)
    for (unsigned i4 = t; i4 * 4u < m; i4 += 1024u)
        *reinterpret_cast<uint4*>(&srcsort[base + i4 * 4u]) =
            *reinterpret_cast<const uint4*>(&stg[i4 * 4u]);
}

// ---------------- layer 1 transform: hs1b = bf16((x @ W1) * dinv) ----------------
__global__ __launch_bounds__(256) void k_gemm1(const float* __restrict__ x,
                                               const float* __restrict__ W1,
                                               const float* __restrict__ dinv,
                                               unsigned* __restrict__ hs1b) {
    __shared__ float w1s[FIN * HID];
    __shared__ float xs[64 * 132];
    int t = threadIdx.x;
    int r0 = blockIdx.x * 64;
    for (int i = t; i < FIN * HID; i += 256) w1s[i] = W1[i];
    int maxr = NN - r0; if (maxr > 64) maxr = 64;
    const float4* x4 = reinterpret_cast<const float4*>(x + (size_t)r0 * FIN);
    #pragma unroll
    for (int i = 0; i < 8; ++i) {
        int fi = t + i * 256;
        int f = fi * 4;
        int r = f >> 7, k = f & 127;
        if (r < maxr) {
            float4 v = x4[fi];
            *reinterpret_cast<float4*>(&xs[r * 132 + k]) = v;
        }
    }
    __syncthreads();
    int r = t >> 2;
    int cg = (t & 3) * 4;
    if (r < maxr) {
        float4 acc = {0.f, 0.f, 0.f, 0.f};
        const float* xr = &xs[r * 132];
        #pragma unroll 4
        for (int k = 0; k < FIN; ++k) {
            float xv = xr[k];
            const float4 w = *reinterpret_cast<const float4*>(&w1s[k * HID + cg]);
            acc.x += xv * w.x; acc.y += xv * w.y; acc.z += xv * w.z; acc.w += xv * w.w;
        }
        int rr = r0 + r;
        float di = dinv[rr];
        uint2 pk;
        pk.x = bf16pair(acc.x * di, acc.y * di);
        pk.y = bf16pair(acc.z * di, acc.w * di);
        *reinterpret_cast<uint2*>(&hs1b[(rr << 3) + (cg >> 1)]) = pk;
    }
}

// ---------------- layer 1 aggregate (LDS-staged edge list, bf16 gather) + W2 ----------------
// 256 threads = 32 nodes x 8 lanes; block's 32 nodes share one contiguous srcsort run
__global__ __launch_bounds__(256) void k_l1(const uint2* __restrict__ row_se,
                                            const unsigned* __restrict__ srcsort,
                                            const unsigned* __restrict__ hs1b,
                                            const float* __restrict__ dinv,
                                            const float* __restrict__ W2,
                                            const float* __restrict__ b1,
                                            unsigned* __restrict__ hs2b) {
    __shared__ float htile[32 * 17];
    __shared__ float w2s[HID * NC];
    __shared__ unsigned estg[LCH1];
    __shared__ unsigned sh_lo, sh_hi;
    int t = threadIdx.x;
    if (t < HID * NC) w2s[t] = W2[t];
    int g = t >> 3;          // node in block 0..31
    int c2 = t & 7;          // uint index (2 channels)
    int n = blockIdx.x * 32 + g;   // grid 3125*32 == NN
    uint2 se = row_se[n];
    if (t == 0)   sh_lo = row_se[blockIdx.x * 32].x;
    if (t == 255) sh_hi = row_se[blockIdx.x * 32 + 31].y;
    __syncthreads();
    unsigned lo = sh_lo, hi = sh_hi;
    float a0 = 0.f, a1 = 0.f;
    for (unsigned cb = lo; cb < hi; cb += LCH1) {
        unsigned cnt = hi - cb; if (cnt > LCH1) cnt = LCH1;
        // coalesced stage of the block's edge run
        for (unsigned i = t; i < cnt; i += 256) estg[i] = srcsort[cb + i];
        __syncthreads();
        unsigned es = se.x > cb ? se.x : cb;
        unsigned ee = se.y < cb + cnt ? se.y : cb + cnt;
        unsigned e = es;
        for (; e + 3 < ee; e += 4) {
            int s0 = estg[e - cb];
            int s1 = estg[e + 1 - cb];
            int s2 = estg[e + 2 - cb];
            int s3 = estg[e + 3 - cb];
            unsigned v0 = hs1b[(s0 << 3) + c2];
            unsigned v1 = hs1b[(s1 << 3) + c2];
            unsigned v2 = hs1b[(s2 << 3) + c2];
            unsigned v3 = hs1b[(s3 << 3) + c2];
            a0 += __uint_as_float(v0 << 16) + __uint_as_float(v1 << 16)
                + __uint_as_float(v2 << 16) + __uint_as_float(v3 << 16);
            a1 += __uint_as_float(v0 & 0xffff0000u) + __uint_as_float(v1 & 0xffff0000u)
                + __uint_as_float(v2 & 0xffff0000u) + __uint_as_float(v3 & 0xffff0000u);
        }
        for (; e < ee; ++e) {
            unsigned v = hs1b[((int)estg[e - cb] << 3) + c2];
            a0 += __uint_as_float(v << 16);
            a1 += __uint_as_float(v & 0xffff0000u);
        }
        __syncthreads();   // protect estg before next stage
    }
    {   // self-loop
        unsigned v = hs1b[(n << 3) + c2];
        a0 += __uint_as_float(v << 16);
        a1 += __uint_as_float(v & 0xffff0000u);
    }
    float di = dinv[n];
    int c = c2 * 2;
    htile[g * 17 + c]     = fmaxf(a0 * di + b1[c], 0.f);
    htile[g * 17 + c + 1] = fmaxf(a1 * di + b1[c + 1], 0.f);
    __syncthreads();
    if (t < 128) {
        int n2 = t >> 2, j2 = t & 3;     // node 0..31, output pair 0..3
        const float* hr = &htile[n2 * 17];
        float oa = 0.f, ob = 0.f;
        #pragma unroll
        for (int k = 0; k < HID; ++k) {
            float hv = hr[k];
            oa += hv * w2s[k * NC + 2 * j2];
            ob += hv * w2s[k * NC + 2 * j2 + 1];
        }
        int node2 = blockIdx.x * 32 + n2;
        float d2 = dinv[node2];
        hs2b[(node2 << 2) + j2] = bf16pair(oa * d2, ob * d2);
    }
}

// ---------------- layer 2 aggregate (LDS-staged edges) + log_softmax ----------------
// 256 threads = 64 nodes x 4 lanes
__global__ __launch_bounds__(256) void k_l2(const uint2* __restrict__ row_se,
                                            const unsigned* __restrict__ srcsort,
                                            const unsigned* __restrict__ hs2b,
                                            const float* __restrict__ dinv,
                                            const float* __restrict__ b2,
                                            float* __restrict__ out) {
    __shared__ unsigned estg[LCH2];
    __shared__ unsigned sh_lo, sh_hi;
    int t = threadIdx.x;
    int g = t >> 2;          // node in block 0..63
    int c2 = t & 3;          // uint index (2 channels)
    int n0 = blockIdx.x * 64;
    int n = n0 + g;
    uint2 se = (n < NN) ? row_se[n] : uint2{0u, 0u};
    if (t == 0)   sh_lo = row_se[n0].x;
    if (t == 255) { int nl = n0 + 63; if (nl >= NN) nl = NN - 1; sh_hi = row_se[nl].y; }
    __syncthreads();
    unsigned lo = sh_lo, hi = sh_hi;
    float a0 = 0.f, a1 = 0.f;
    for (unsigned cb = lo; cb < hi; cb += LCH2) {
        unsigned cnt = hi - cb; if (cnt > LCH2) cnt = LCH2;
        for (unsigned i = t; i < cnt; i += 256) estg[i] = srcsort[cb + i];
        __syncthreads();
        unsigned es = se.x > cb ? se.x : cb;
        unsigned ee = se.y < cb + cnt ? se.y : cb + cnt;
        unsigned e = es;
        for (; e + 3 < ee && e + 3 >= e; e += 4) {
            int s0 = estg[e - cb];
            int s1 = estg[e + 1 - cb];
            int s2 = estg[e + 2 - cb];
            int s3 = estg[e + 3 - cb];
            unsigned v0 = hs2b[(s0 << 2) + c2];
            unsigned v1 = hs2b[(s1 << 2) + c2];
            unsigned v2 = hs2b[(s2 << 2) + c2];
            unsigned v3 = hs2b[(s3 << 2) + c2];
            a0 += __uint_as_float(v0 << 16) + __uint_as_float(v1 << 16)
                + __uint_as_float(v2 << 16) + __uint_as_float(v3 << 16);
            a1 += __uint_as_float(v0 & 0xffff0000u) + __uint_as_float(v1 & 0xffff0000u)
                + __uint_as_float(v2 & 0xffff0000u) + __uint_as_float(v3 & 0xffff0000u);
        }
        for (; e < ee; ++e) {
            unsigned v = hs2b[((int)estg[e - cb] << 2) + c2];
            a0 += __uint_as_float(v << 16);
            a1 += __uint_as_float(v & 0xffff0000u);
        }
        __syncthreads();
    }
    if (n >= NN) return;
    {   // self-loop
        unsigned v = hs2b[(n << 2) + c2];
        a0 += __uint_as_float(v << 16);
        a1 += __uint_as_float(v & 0xffff0000u);
    }
    float di = dinv[n];
    int c = c2 * 2;
    float v0 = a0 * di + b2[c];
    float v1 = a1 * di + b2[c + 1];
    float m = fmaxf(v0, v1);
    m = fmaxf(m, __shfl_xor(m, 1, 4));
    m = fmaxf(m, __shfl_xor(m, 2, 4));
    float s = expf(v0 - m) + expf(v1 - m);
    s += __shfl_xor(s, 1, 4);
    s += __shfl_xor(s, 2, 4);
    float ls = logf(s);
    float2 o = {v0 - m - ls, v1 - m - ls};
    *reinterpret_cast<float2*>(&out[(n << 3) + c]) = o;
}

extern "C" void kernel_launch(void* const* d_in, const int* in_sizes, int n_in,
                              void* d_out, int out_size, void* d_ws, size_t ws_size,
                              hipStream_t stream) {
    const float* x   = (const float*)d_in[0];
    const int*   ei  = (const int*)d_in[1];
    const float* W1  = (const float*)d_in[2];
    const float* b1  = (const float*)d_in[3];
    const float* W2  = (const float*)d_in[4];
    const float* b2  = (const float*)d_in[5];
    float* out = (float*)d_out;

    const int* row = ei;
    const int* col = ei + EE;

    // ws layout (4-byte units)
    float*    ws      = (float*)d_ws;
    float*    dinv    = ws;                                    // NN
    unsigned* hs1b    = (unsigned*)(dinv + NN);                // NN*8 (bf16 x16)
    unsigned* hs2b    = hs1b + (size_t)NN * 8;                 // NN*4 (bf16 x8)
    uint2*    row_se  = (uint2*)(hs2b + (size_t)NN * 4);       // NN uint2
    unsigned* cursor  = (unsigned*)(row_se + NN);              // NBUK
    unsigned* bins_pk = cursor + NBUK + 1;                     // NBUK*CAP slab (16B-aligned)
    unsigned* srcsort = bins_pk + (size_t)NBUK * CAP;          // NBUK*CAP slab

    hipMemsetAsync(cursor, 0, NBUK * sizeof(unsigned), stream);
    k_binscatter  <<<NBLK, 1024, 0, stream>>>(row, col, cursor, bins_pk);
    k_build       <<<NBUK, 1024, 0, stream>>>(bins_pk, cursor, row_se, dinv, srcsort);
    k_gemm1       <<<(NN + 63) / 64, 256, 0, stream>>>(x, W1, dinv, hs1b);
    k_l1          <<<NN / 32, 256, 0, stream>>>(row_se, srcsort, hs1b, dinv, W2, b1, hs2b);
    k_l2          <<<(NN + 127) / 128 * 2, 256, 0, stream>>>(row_se, srcsort, hs2b, dinv, b2, out);
}

// Round 13
// 103.559 us; speedup vs baseline: 34.3482x; 34.3482x over previous
//
#include <hip/hip_runtime.h>

#define NN 100000
#define EE 3200000
#define FIN 128
#define HID 16
#define NC 8

#define CHUNK 12500
#define NBLK 256                           // CHUNK*NBLK == EE exactly
#define BW 256                             // nodes per bucket
#define NBUK ((NN + BW - 1) / BW)          // 391
#define EPT 13                             // ceil(CHUNK/1024)
#define CAP 9216                           // bucket slab capacity (mean 8184, sigma 90 -> 11 sigma)
#define LCH1 2048                          // l1 edge-stage capacity (block mean 1024, sd 32)
#define LCH2 3072                          // l2 edge-stage capacity (block mean 2096, sd 46)

// pack two floats into bf16x2 (round-to-nearest-even)
__device__ __forceinline__ unsigned bf16pair(float a, float b) {
    unsigned ua = __float_as_uint(a), ub = __float_as_uint(b);
    ua = ua + 0x7fffu + ((ua >> 16) & 1u);
    ub = ub + 0x7fffu + ((ub >> 16) & 1u);
    return (ua >> 16) | (ub & 0xffff0000u);
}

// ---------------- pass 1: LDS chunk sort + ticket slab allocation + coalesced writeout ----
// bins_pk[slot] = src | (dst & 255) << 17   (src < 2^17, dl < 2^8)
__global__ __launch_bounds__(1024) void k_binscatter(const int* __restrict__ row,
                                                     const int* __restrict__ col,
                                                     unsigned* __restrict__ cursor,
                                                     unsigned* __restrict__ bins_pk) {
    __shared__ unsigned s_cnt[NBUK];     // raw counts -> (after scan) inclusive
    __shared__ unsigned s_off[NBUK];     // running rank (starts at exclusive start)
    __shared__ unsigned s_gb[NBUK];      // ticket -> folded dest bias (b*CAP + gb - start)
    __shared__ unsigned stg[CHUNK];                 // 50 KB
    __shared__ unsigned short bktid[CHUNK];         // 25 KB
    int t = threadIdx.x;
    for (int i = t; i < NBUK; i += 1024) s_cnt[i] = 0u;
    __syncthreads();
    int base = blockIdx.x * CHUNK;
    unsigned val[EPT];
    unsigned short bk[EPT];
    #pragma unroll
    for (int k = 0; k < EPT; ++k) {
        int i = t + k * 1024;
        if (i < CHUNK) {
            int s = row[base + i];
            int d = col[base + i];
            unsigned b = (unsigned)d >> 8;
            val[k] = (unsigned)s | ((unsigned)(d & 255) << 17);
            bk[k] = (unsigned short)b;
            atomicAdd(&s_cnt[b], 1u);
        }
    }
    __syncthreads();
    // ticket: reserve a contiguous run in each bucket's slab (s_cnt still raw)
    for (int i = t; i < NBUK; i += 1024)
        s_gb[i] = atomicAdd(&cursor[i], s_cnt[i]);
    __syncthreads();
    // inclusive scan s_cnt over NBUK entries
    for (int off = 1; off < NBUK; off <<= 1) {
        unsigned v = 0u;
        if (t < NBUK && t >= off) v = s_cnt[t - off];
        __syncthreads();
        if (t < NBUK) s_cnt[t] += v;
        __syncthreads();
    }
    if (t < NBUK) {
        unsigned st = (t == 0) ? 0u : s_cnt[t - 1];
        s_off[t] = st;
        s_gb[t] = (unsigned)t * CAP + s_gb[t] - st;   // folded dest bias
    }
    __syncthreads();
    // rank-scatter into LDS stage
    #pragma unroll
    for (int k = 0; k < EPT; ++k) {
        int i = t + k * 1024;
        if (i < CHUNK) {
            unsigned b = bk[k];
            unsigned r = atomicAdd(&s_off[b], 1u);
            stg[r] = val[k];
            bktid[r] = (unsigned short)b;
        }
    }
    __syncthreads();
    // coalesced writeout into bucket slabs
    for (int i = t; i < CHUNK; i += 1024) {
        unsigned b = bktid[i];
        bins_pk[s_gb[b] + (unsigned)i] = stg[i];
    }
}

// ---------------- pass 2: per-bucket CSR build (uint4 slab IO, LDS stage) ----------------
__global__ __launch_bounds__(1024) void k_build(const unsigned* __restrict__ bins_pk,
                                                const unsigned* __restrict__ cursor,
                                                uint2* __restrict__ row_se,
                                                float* __restrict__ dinv,
                                                unsigned* __restrict__ srcsort) {
    __shared__ unsigned cnt[BW];       // per-node count -> inclusive scan
    __shared__ unsigned offn[BW];      // running rank
    __shared__ unsigned stg[CAP];      // 36 KB
    int t = threadIdx.x, b = blockIdx.x;
    if (t < BW) cnt[t] = 0u;
    __syncthreads();
    unsigned m = cursor[b];
    unsigned base = (unsigned)b * CAP;
    uint4 w4[3];                       // 3*1024*4 = 12288 covers CAP
    #pragma unroll
    for (int k = 0; k < 3; ++k) {
        unsigned i = (unsigned)(t + k * 1024) * 4u;
        if (i < m) {
            w4[k] = *reinterpret_cast<const uint4*>(&bins_pk[base + i]);
            atomicAdd(&cnt[w4[k].x >> 17], 1u);
            if (i + 1 < m) atomicAdd(&cnt[w4[k].y >> 17], 1u);
            if (i + 2 < m) atomicAdd(&cnt[w4[k].z >> 17], 1u);
            if (i + 3 < m) atomicAdd(&cnt[w4[k].w >> 17], 1u);
        }
    }
    __syncthreads();
    // inclusive scan over BW entries
    for (int off = 1; off < BW; off <<= 1) {
        unsigned v = 0u;
        if (t < BW && t >= off) v = cnt[t - off];
        __syncthreads();
        if (t < BW) cnt[t] += v;
        __syncthreads();
    }
    if (t < BW) {
        unsigned st = (t == 0) ? 0u : cnt[t - 1];
        offn[t] = st;
        int node = b * BW + t;
        if (node < NN) {
            row_se[node] = uint2{base + st, base + cnt[t]};
            dinv[node] = rsqrtf(1.0f + (float)(cnt[t] - st));
        }
    }
    __syncthreads();
    // rank-scatter into LDS stage (in-bucket final order)
    #pragma unroll
    for (int k = 0; k < 3; ++k) {
        unsigned i = (unsigned)(t + k * 1024) * 4u;
        if (i < m) {
            unsigned r;
            r = atomicAdd(&offn[w4[k].x >> 17], 1u); stg[r] = w4[k].x & 0x1FFFFu;
            if (i + 1 < m) { r = atomicAdd(&offn[w4[k].y >> 17], 1u); stg[r] = w4[k].y & 0x1FFFFu; }
            if (i + 2 < m) { r = atomicAdd(&offn[w4[k].z >> 17], 1u); stg[r] = w4[k].z & 0x1FFFFu; }
            if (i + 3 < m) { r = atomicAdd(&offn[w4[k].w >> 17], 1u); stg[r] = w4[k].w & 0x1FFFFu; }
        }
    }
    __syncthreads();
    // sequential uint4 writeout (pad words land in never-read slab padding)
    for (unsigned i4 = t; i4 * 4u < m; i4 += 1024u)
        *reinterpret_cast<uint4*>(&srcsort[base + i4 * 4u]) =
            *reinterpret_cast<const uint4*>(&stg[i4 * 4u]);
}

// ---------------- layer 1 transform: hs1b = bf16((x @ W1) * dinv) ----------------
__global__ __launch_bounds__(256) void k_gemm1(const float* __restrict__ x,
                                               const float* __restrict__ W1,
                                               const float* __restrict__ dinv,
                                               unsigned* __restrict__ hs1b) {
    __shared__ float w1s[FIN * HID];
    __shared__ float xs[64 * 132];
    int t = threadIdx.x;
    int r0 = blockIdx.x * 64;
    for (int i = t; i < FIN * HID; i += 256) w1s[i] = W1[i];
    int maxr = NN - r0; if (maxr > 64) maxr = 64;
    const float4* x4 = reinterpret_cast<const float4*>(x + (size_t)r0 * FIN);
    #pragma unroll
    for (int i = 0; i < 8; ++i) {
        int fi = t + i * 256;
        int f = fi * 4;
        int r = f >> 7, k = f & 127;
        if (r < maxr) {
            float4 v = x4[fi];
            *reinterpret_cast<float4*>(&xs[r * 132 + k]) = v;
        }
    }
    __syncthreads();
    int r = t >> 2;
    int cg = (t & 3) * 4;
    if (r < maxr) {
        float4 acc = {0.f, 0.f, 0.f, 0.f};
        const float* xr = &xs[r * 132];
        #pragma unroll 4
        for (int k = 0; k < FIN; ++k) {
            float xv = xr[k];
            const float4 w = *reinterpret_cast<const float4*>(&w1s[k * HID + cg]);
            acc.x += xv * w.x; acc.y += xv * w.y; acc.z += xv * w.z; acc.w += xv * w.w;
        }
        int rr = r0 + r;
        float di = dinv[rr];
        uint2 pk;
        pk.x = bf16pair(acc.x * di, acc.y * di);
        pk.y = bf16pair(acc.z * di, acc.w * di);
        *reinterpret_cast<uint2*>(&hs1b[(rr << 3) + (cg >> 1)]) = pk;
    }
}

// ---------------- layer 1 aggregate (LDS-staged edge list, bf16 gather) + W2 ----------------
// 256 threads = 32 nodes x 8 lanes; block's 32 nodes share one contiguous srcsort run
__global__ __launch_bounds__(256) void k_l1(const uint2* __restrict__ row_se,
                                            const unsigned* __restrict__ srcsort,
                                            const unsigned* __restrict__ hs1b,
                                            const float* __restrict__ dinv,
                                            const float* __restrict__ W2,
                                            const float* __restrict__ b1,
                                            unsigned* __restrict__ hs2b) {
    __shared__ float htile[32 * 17];
    __shared__ float w2s[HID * NC];
    __shared__ unsigned estg[LCH1];
    __shared__ unsigned sh_lo, sh_hi;
    int t = threadIdx.x;
    if (t < HID * NC) w2s[t] = W2[t];
    int g = t >> 3;          // node in block 0..31
    int c2 = t & 7;          // uint index (2 channels)
    int n = blockIdx.x * 32 + g;   // grid 3125*32 == NN exactly -> always valid
    uint2 se = row_se[n];
    if (t == 0)   sh_lo = row_se[blockIdx.x * 32].x;
    if (t == 255) sh_hi = row_se[blockIdx.x * 32 + 31].y;
    __syncthreads();
    unsigned lo = sh_lo, hi = sh_hi;
    float a0 = 0.f, a1 = 0.f;
    for (unsigned cb = lo; cb < hi; cb += LCH1) {
        unsigned cnt = hi - cb; if (cnt > LCH1) cnt = LCH1;
        // coalesced stage of the block's edge run
        for (unsigned i = t; i < cnt; i += 256) estg[i] = srcsort[cb + i];
        __syncthreads();
        unsigned es = se.x > cb ? se.x : cb;
        unsigned ee = se.y < cb + cnt ? se.y : cb + cnt;
        unsigned e = es;
        for (; e + 3 < ee; e += 4) {
            int s0 = estg[e - cb];
            int s1 = estg[e + 1 - cb];
            int s2 = estg[e + 2 - cb];
            int s3 = estg[e + 3 - cb];
            unsigned v0 = hs1b[(s0 << 3) + c2];
            unsigned v1 = hs1b[(s1 << 3) + c2];
            unsigned v2 = hs1b[(s2 << 3) + c2];
            unsigned v3 = hs1b[(s3 << 3) + c2];
            a0 += __uint_as_float(v0 << 16) + __uint_as_float(v1 << 16)
                + __uint_as_float(v2 << 16) + __uint_as_float(v3 << 16);
            a1 += __uint_as_float(v0 & 0xffff0000u) + __uint_as_float(v1 & 0xffff0000u)
                + __uint_as_float(v2 & 0xffff0000u) + __uint_as_float(v3 & 0xffff0000u);
        }
        for (; e < ee; ++e) {
            unsigned v = hs1b[((int)estg[e - cb] << 3) + c2];
            a0 += __uint_as_float(v << 16);
            a1 += __uint_as_float(v & 0xffff0000u);
        }
        __syncthreads();   // protect estg before next stage
    }
    {   // self-loop
        unsigned v = hs1b[(n << 3) + c2];
        a0 += __uint_as_float(v << 16);
        a1 += __uint_as_float(v & 0xffff0000u);
    }
    float di = dinv[n];
    int c = c2 * 2;
    htile[g * 17 + c]     = fmaxf(a0 * di + b1[c], 0.f);
    htile[g * 17 + c + 1] = fmaxf(a1 * di + b1[c + 1], 0.f);
    __syncthreads();
    if (t < 128) {
        int n2 = t >> 2, j2 = t & 3;     // node 0..31, output pair 0..3
        const float* hr = &htile[n2 * 17];
        float oa = 0.f, ob = 0.f;
        #pragma unroll
        for (int k = 0; k < HID; ++k) {
            float hv = hr[k];
            oa += hv * w2s[k * NC + 2 * j2];
            ob += hv * w2s[k * NC + 2 * j2 + 1];
        }
        int node2 = blockIdx.x * 32 + n2;
        float d2 = dinv[node2];
        hs2b[(node2 << 2) + j2] = bf16pair(oa * d2, ob * d2);
    }
}

// ---------------- layer 2 aggregate (LDS-staged edges) + log_softmax ----------------
// 256 threads = 64 nodes x 4 lanes
__global__ __launch_bounds__(256) void k_l2(const uint2* __restrict__ row_se,
                                            const unsigned* __restrict__ srcsort,
                                            const unsigned* __restrict__ hs2b,
                                            const float* __restrict__ dinv,
                                            const float* __restrict__ b2,
                                            float* __restrict__ out) {
    __shared__ unsigned estg[LCH2];
    __shared__ unsigned sh_lo, sh_hi;
    int t = threadIdx.x;
    int g = t >> 2;          // node in block 0..63
    int c2 = t & 3;          // uint index (2 channels)
    int n0 = blockIdx.x * 64;
    if (n0 >= NN) return;    // BUGFIX R12: last block (n0=100032) read past row_se
                             // into cursor[], giving lo~8k / hi~3.59M -> one block
                             // swept all of srcsort for 3.6 ms. Uniform exit, pre-barrier.
    int n = n0 + g;
    uint2 se = (n < NN) ? row_se[n] : uint2{0u, 0u};
    if (t == 0)   sh_lo = row_se[n0].x;
    if (t == 255) { int nl = n0 + 63; if (nl >= NN) nl = NN - 1; sh_hi = row_se[nl].y; }
    __syncthreads();
    unsigned lo = sh_lo, hi = sh_hi;
    float a0 = 0.f, a1 = 0.f;
    for (unsigned cb = lo; cb < hi; cb += LCH2) {
        unsigned cnt = hi - cb; if (cnt > LCH2) cnt = LCH2;
        for (unsigned i = t; i < cnt; i += 256) estg[i] = srcsort[cb + i];
        __syncthreads();
        unsigned es = se.x > cb ? se.x : cb;
        unsigned ee = se.y < cb + cnt ? se.y : cb + cnt;
        unsigned e = es;
        for (; e + 3 < ee; e += 4) {
            int s0 = estg[e - cb];
            int s1 = estg[e + 1 - cb];
            int s2 = estg[e + 2 - cb];
            int s3 = estg[e + 3 - cb];
            unsigned v0 = hs2b[(s0 << 2) + c2];
            unsigned v1 = hs2b[(s1 << 2) + c2];
            unsigned v2 = hs2b[(s2 << 2) + c2];
            unsigned v3 = hs2b[(s3 << 2) + c2];
            a0 += __uint_as_float(v0 << 16) + __uint_as_float(v1 << 16)
                + __uint_as_float(v2 << 16) + __uint_as_float(v3 << 16);
            a1 += __uint_as_float(v0 & 0xffff0000u) + __uint_as_float(v1 & 0xffff0000u)
                + __uint_as_float(v2 & 0xffff0000u) + __uint_as_float(v3 & 0xffff0000u);
        }
        for (; e < ee; ++e) {
            unsigned v = hs2b[((int)estg[e - cb] << 2) + c2];
            a0 += __uint_as_float(v << 16);
            a1 += __uint_as_float(v & 0xffff0000u);
        }
        __syncthreads();
    }
    if (n >= NN) return;
    {   // self-loop
        unsigned v = hs2b[(n << 2) + c2];
        a0 += __uint_as_float(v << 16);
        a1 += __uint_as_float(v & 0xffff0000u);
    }
    float di = dinv[n];
    int c = c2 * 2;
    float v0 = a0 * di + b2[c];
    float v1 = a1 * di + b2[c + 1];
    float m = fmaxf(v0, v1);
    m = fmaxf(m, __shfl_xor(m, 1, 4));
    m = fmaxf(m, __shfl_xor(m, 2, 4));
    float s = expf(v0 - m) + expf(v1 - m);
    s += __shfl_xor(s, 1, 4);
    s += __shfl_xor(s, 2, 4);
    float ls = logf(s);
    float2 o = {v0 - m - ls, v1 - m - ls};
    *reinterpret_cast<float2*>(&out[(n << 3) + c]) = o;
}

extern "C" void kernel_launch(void* const* d_in, const int* in_sizes, int n_in,
                              void* d_out, int out_size, void* d_ws, size_t ws_size,
                              hipStream_t stream) {
    const float* x   = (const float*)d_in[0];
    const int*   ei  = (const int*)d_in[1];
    const float* W1  = (const float*)d_in[2];
    const float* b1  = (const float*)d_in[3];
    const float* W2  = (const float*)d_in[4];
    const float* b2  = (const float*)d_in[5];
    float* out = (float*)d_out;

    const int* row = ei;
    const int* col = ei + EE;

    // ws layout (4-byte units)
    float*    ws      = (float*)d_ws;
    float*    dinv    = ws;                                    // NN
    unsigned* hs1b    = (unsigned*)(dinv + NN);                // NN*8 (bf16 x16)
    unsigned* hs2b    = hs1b + (size_t)NN * 8;                 // NN*4 (bf16 x8)
    uint2*    row_se  = (uint2*)(hs2b + (size_t)NN * 4);       // NN uint2
    unsigned* cursor  = (unsigned*)(row_se + NN);              // NBUK
    unsigned* bins_pk = cursor + NBUK + 1;                     // NBUK*CAP slab (16B-aligned)
    unsigned* srcsort = bins_pk + (size_t)NBUK * CAP;          // NBUK*CAP slab

    hipMemsetAsync(cursor, 0, NBUK * sizeof(unsigned), stream);
    k_binscatter  <<<NBLK, 1024, 0, stream>>>(row, col, cursor, bins_pk);
    k_build       <<<NBUK, 1024, 0, stream>>>(bins_pk, cursor, row_se, dinv, srcsort);
    k_gemm1       <<<(NN + 63) / 64, 256, 0, stream>>>(x, W1, dinv, hs1b);
    k_l1          <<<NN / 32, 256, 0, stream>>>(row_se, srcsort, hs1b, dinv, W2, b1, hs2b);
    k_l2          <<<(NN + 63) / 64, 256, 0, stream>>>(row_se, srcsort, hs2b, dinv, b2, out);
}

// Round 14
// 99.700 us; speedup vs baseline: 35.6777x; 1.0387x over previous
//
#include <hip/hip_runtime.h>

#define NN 100000
#define EE 3200000
#define FIN 128
#define HID 16
#define NC 8

#define CHUNK 12500
#define CHUNK4 3125                        // CHUNK/4 (exact)
#define NBLK 256                           // CHUNK*NBLK == EE exactly
#define BW 256                             // nodes per bucket
#define NBUK ((NN + BW - 1) / BW)          // 391
#define CAP 9216                           // bucket slab capacity (mean 8184, sigma 90 -> 11 sigma)
#define LCH1 2048                          // l1 edge-stage capacity (block mean 1024, sd 32)
#define LCH2 3072                          // l2 edge-stage capacity (block mean 2096, sd 46)

// pack two floats into bf16x2 (round-to-nearest-even)
__device__ __forceinline__ unsigned bf16pair(float a, float b) {
    unsigned ua = __float_as_uint(a), ub = __float_as_uint(b);
    ua = ua + 0x7fffu + ((ua >> 16) & 1u);
    ub = ub + 0x7fffu + ((ub >> 16) & 1u);
    return (ua >> 16) | (ub & 0xffff0000u);
}

// inclusive scan across the 64-lane wave
__device__ __forceinline__ unsigned wave_iscan(unsigned v, int lane) {
    #pragma unroll
    for (int d = 1; d < 64; d <<= 1) {
        unsigned u = __shfl_up(v, d, 64);
        if (lane >= d) v += u;
    }
    return v;
}

// ---------------- pass 1: LDS chunk sort + ticket slab allocation + coalesced writeout ----
// bins_pk[slot] = src | (dst & 255) << 17   (src < 2^17, dl < 2^8)
__global__ __launch_bounds__(1024) void k_binscatter(const int* __restrict__ row,
                                                     const int* __restrict__ col,
                                                     unsigned* __restrict__ cursor,
                                                     unsigned* __restrict__ bins_pk) {
    __shared__ unsigned s_cnt[NBUK];     // raw per-bucket counts
    __shared__ unsigned s_off[NBUK];     // running rank (starts at exclusive start)
    __shared__ unsigned s_gb[NBUK];      // folded dest bias (b*CAP + ticket - start)
    __shared__ unsigned s_part[16];      // per-wave scan partials
    __shared__ unsigned stg[CHUNK];                 // 50 KB
    __shared__ unsigned short bktid[CHUNK];         // 25 KB
    int t = threadIdx.x;
    int lane = t & 63, w = t >> 6;
    for (int i = t; i < NBUK; i += 1024) s_cnt[i] = 0u;
    __syncthreads();
    const int4* row4 = reinterpret_cast<const int4*>(row + blockIdx.x * CHUNK);
    const int4* col4 = reinterpret_cast<const int4*>(col + blockIdx.x * CHUNK);
    unsigned val[16];
    unsigned short bk[16];
    #pragma unroll
    for (int k = 0; k < 4; ++k) {
        int i4 = t + k * 1024;
        if (i4 < CHUNK4) {
            int4 r4 = row4[i4];
            int4 c4 = col4[i4];
            int ss[4] = {r4.x, r4.y, r4.z, r4.w};
            int dd[4] = {c4.x, c4.y, c4.z, c4.w};
            #pragma unroll
            for (int j = 0; j < 4; ++j) {
                unsigned b = (unsigned)dd[j] >> 8;
                val[k * 4 + j] = (unsigned)ss[j] | ((unsigned)(dd[j] & 255) << 17);
                bk[k * 4 + j] = (unsigned short)b;
                atomicAdd(&s_cnt[b], 1u);
            }
        }
    }
    __syncthreads();
    // ticket (register-held) + wave-level scan
    unsigned gb = 0u;
    if (t < NBUK) gb = atomicAdd(&cursor[t], s_cnt[t]);
    unsigned v = (t < NBUK) ? s_cnt[t] : 0u;
    unsigned isc = wave_iscan(v, lane);
    if (lane == 63) s_part[w] = isc;
    __syncthreads();
    if (t < NBUK) {
        unsigned ew = 0u;
        #pragma unroll
        for (int i = 0; i < 7; ++i) if (i < w) ew += s_part[i];
        unsigned st = isc + ew - v;              // exclusive start in stg
        s_off[t] = st;
        s_gb[t] = (unsigned)t * CAP + gb - st;   // folded dest bias
    }
    __syncthreads();
    // rank-scatter into LDS stage
    #pragma unroll
    for (int k = 0; k < 4; ++k) {
        int i4 = t + k * 1024;
        if (i4 < CHUNK4) {
            #pragma unroll
            for (int j = 0; j < 4; ++j) {
                unsigned b = bk[k * 4 + j];
                unsigned r = atomicAdd(&s_off[b], 1u);
                stg[r] = val[k * 4 + j];
                bktid[r] = (unsigned short)b;
            }
        }
    }
    __syncthreads();
    // coalesced writeout into bucket slabs
    for (int i = t; i < CHUNK; i += 1024) {
        unsigned b = bktid[i];
        bins_pk[s_gb[b] + (unsigned)i] = stg[i];
    }
}

// ---------------- pass 2: per-bucket CSR build (uint4 slab IO, LDS stage) ----------------
__global__ __launch_bounds__(1024) void k_build(const unsigned* __restrict__ bins_pk,
                                                const unsigned* __restrict__ cursor,
                                                uint2* __restrict__ row_se,
                                                float* __restrict__ dinv,
                                                unsigned* __restrict__ srcsort) {
    __shared__ unsigned cnt[BW];       // per-node raw count
    __shared__ unsigned offn[BW];      // running rank
    __shared__ unsigned s_part[16];
    __shared__ unsigned stg[CAP];      // 36 KB
    int t = threadIdx.x, b = blockIdx.x;
    int lane = t & 63, w = t >> 6;
    if (t < BW) cnt[t] = 0u;
    __syncthreads();
    unsigned m = cursor[b];
    unsigned base = (unsigned)b * CAP;
    uint4 w4[3];                       // 3*1024*4 = 12288 covers CAP
    #pragma unroll
    for (int k = 0; k < 3; ++k) {
        unsigned i = (unsigned)(t + k * 1024) * 4u;
        if (i < m) {
            w4[k] = *reinterpret_cast<const uint4*>(&bins_pk[base + i]);
            atomicAdd(&cnt[w4[k].x >> 17], 1u);
            if (i + 1 < m) atomicAdd(&cnt[w4[k].y >> 17], 1u);
            if (i + 2 < m) atomicAdd(&cnt[w4[k].z >> 17], 1u);
            if (i + 3 < m) atomicAdd(&cnt[w4[k].w >> 17], 1u);
        }
    }
    __syncthreads();
    // wave-level scan over BW entries (waves 0..3)
    unsigned v = (t < BW) ? cnt[t] : 0u;
    unsigned isc = wave_iscan(v, lane);
    if (lane == 63 && w < 4) s_part[w] = isc;
    __syncthreads();
    if (t < BW) {
        unsigned ew = 0u;
        #pragma unroll
        for (int i = 0; i < 3; ++i) if (i < w) ew += s_part[i];
        unsigned incl = isc + ew;
        unsigned st = incl - v;
        offn[t] = st;
        int node = b * BW + t;
        if (node < NN) {
            row_se[node] = uint2{base + st, base + incl};
            dinv[node] = rsqrtf(1.0f + (float)v);
        }
    }
    __syncthreads();
    // rank-scatter into LDS stage (in-bucket final order)
    #pragma unroll
    for (int k = 0; k < 3; ++k) {
        unsigned i = (unsigned)(t + k * 1024) * 4u;
        if (i < m) {
            unsigned r;
            r = atomicAdd(&offn[w4[k].x >> 17], 1u); stg[r] = w4[k].x & 0x1FFFFu;
            if (i + 1 < m) { r = atomicAdd(&offn[w4[k].y >> 17], 1u); stg[r] = w4[k].y & 0x1FFFFu; }
            if (i + 2 < m) { r = atomicAdd(&offn[w4[k].z >> 17], 1u); stg[r] = w4[k].z & 0x1FFFFu; }
            if (i + 3 < m) { r = atomicAdd(&offn[w4[k].w >> 17], 1u); stg[r] = w4[k].w & 0x1FFFFu; }
        }
    }
    __syncthreads();
    // sequential uint4 writeout (pad words land in never-read slab padding)
    for (unsigned i4 = t; i4 * 4u < m; i4 += 1024u)
        *reinterpret_cast<uint4*>(&srcsort[base + i4 * 4u]) =
            *reinterpret_cast<const uint4*>(&stg[i4 * 4u]);
}

// ---------------- layer 1 transform: hs1b = bf16((x @ W1) * dinv) ----------------
__global__ __launch_bounds__(256) void k_gemm1(const float* __restrict__ x,
                                               const float* __restrict__ W1,
                                               const float* __restrict__ dinv,
                                               unsigned* __restrict__ hs1b) {
    __shared__ float w1s[FIN * HID];
    __shared__ float xs[64 * 132];
    int t = threadIdx.x;
    int r0 = blockIdx.x * 64;
    for (int i = t; i < FIN * HID; i += 256) w1s[i] = W1[i];
    int maxr = NN - r0; if (maxr > 64) maxr = 64;
    const float4* x4 = reinterpret_cast<const float4*>(x + (size_t)r0 * FIN);
    #pragma unroll
    for (int i = 0; i < 8; ++i) {
        int fi = t + i * 256;
        int f = fi * 4;
        int r = f >> 7, k = f & 127;
        if (r < maxr) {
            float4 v = x4[fi];
            *reinterpret_cast<float4*>(&xs[r * 132 + k]) = v;
        }
    }
    __syncthreads();
    int r = t >> 2;
    int cg = (t & 3) * 4;
    if (r < maxr) {
        float4 acc = {0.f, 0.f, 0.f, 0.f};
        const float* xr = &xs[r * 132];
        #pragma unroll 4
        for (int k = 0; k < FIN; ++k) {
            float xv = xr[k];
            const float4 w = *reinterpret_cast<const float4*>(&w1s[k * HID + cg]);
            acc.x += xv * w.x; acc.y += xv * w.y; acc.z += xv * w.z; acc.w += xv * w.w;
        }
        int rr = r0 + r;
        float di = dinv[rr];
        uint2 pk;
        pk.x = bf16pair(acc.x * di, acc.y * di);
        pk.y = bf16pair(acc.z * di, acc.w * di);
        *reinterpret_cast<uint2*>(&hs1b[(rr << 3) + (cg >> 1)]) = pk;
    }
}

// ---------------- layer 1 aggregate (LDS-staged edge list, bf16 gather) + W2 ----------------
// 256 threads = 32 nodes x 8 lanes; block's 32 nodes share one contiguous srcsort run
__global__ __launch_bounds__(256) void k_l1(const uint2* __restrict__ row_se,
                                            const unsigned* __restrict__ srcsort,
                                            const unsigned* __restrict__ hs1b,
                                            const float* __restrict__ dinv,
                                            const float* __restrict__ W2,
                                            const float* __restrict__ b1,
                                            unsigned* __restrict__ hs2b) {
    __shared__ float htile[32 * 17];
    __shared__ float w2s[HID * NC];
    __shared__ __attribute__((aligned(16))) unsigned estg[LCH1 + 8];
    __shared__ unsigned sh_lo, sh_hi;
    int t = threadIdx.x;
    if (t < HID * NC) w2s[t] = W2[t];
    int g = t >> 3;          // node in block 0..31
    int c2 = t & 7;          // uint index (2 channels)
    int n = blockIdx.x * 32 + g;   // grid 3125*32 == NN exactly -> always valid
    uint2 se = row_se[n];
    if (t == 0)   sh_lo = row_se[blockIdx.x * 32].x;
    if (t == 255) sh_hi = row_se[blockIdx.x * 32 + 31].y;
    __syncthreads();
    unsigned lo = sh_lo, hi = sh_hi;
    float a0 = 0.f, a1 = 0.f;
    for (unsigned cb = lo; cb < hi; cb += LCH1) {
        unsigned cnt = hi - cb; if (cnt > LCH1) cnt = LCH1;
        unsigned cb0 = cb & ~3u;
        unsigned tot = (cb - cb0) + cnt;
        unsigned n4 = (tot + 3) >> 2;
        // uint4 coalesced stage of the block's edge run
        for (unsigned i = t; i < n4; i += 256)
            *reinterpret_cast<uint4*>(&estg[i << 2]) =
                *reinterpret_cast<const uint4*>(&srcsort[cb0 + (i << 2)]);
        __syncthreads();
        unsigned es = se.x > cb ? se.x : cb;
        unsigned ee = se.y < cb + cnt ? se.y : cb + cnt;
        unsigned e = es;
        for (; e + 3 < ee; e += 4) {
            int s0 = estg[e - cb0];
            int s1 = estg[e + 1 - cb0];
            int s2 = estg[e + 2 - cb0];
            int s3 = estg[e + 3 - cb0];
            unsigned v0 = hs1b[(s0 << 3) + c2];
            unsigned v1 = hs1b[(s1 << 3) + c2];
            unsigned v2 = hs1b[(s2 << 3) + c2];
            unsigned v3 = hs1b[(s3 << 3) + c2];
            a0 += __uint_as_float(v0 << 16) + __uint_as_float(v1 << 16)
                + __uint_as_float(v2 << 16) + __uint_as_float(v3 << 16);
            a1 += __uint_as_float(v0 & 0xffff0000u) + __uint_as_float(v1 & 0xffff0000u)
                + __uint_as_float(v2 & 0xffff0000u) + __uint_as_float(v3 & 0xffff0000u);
        }
        for (; e < ee; ++e) {
            unsigned v = hs1b[((int)estg[e - cb0] << 3) + c2];
            a0 += __uint_as_float(v << 16);
            a1 += __uint_as_float(v & 0xffff0000u);
        }
        __syncthreads();   // protect estg before next stage
    }
    {   // self-loop
        unsigned v = hs1b[(n << 3) + c2];
        a0 += __uint_as_float(v << 16);
        a1 += __uint_as_float(v & 0xffff0000u);
    }
    float di = dinv[n];
    int c = c2 * 2;
    htile[g * 17 + c]     = fmaxf(a0 * di + b1[c], 0.f);
    htile[g * 17 + c + 1] = fmaxf(a1 * di + b1[c + 1], 0.f);
    __syncthreads();
    if (t < 128) {
        int n2 = t >> 2, j2 = t & 3;     // node 0..31, output pair 0..3
        const float* hr = &htile[n2 * 17];
        float oa = 0.f, ob = 0.f;
        #pragma unroll
        for (int k = 0; k < HID; ++k) {
            float hv = hr[k];
            oa += hv * w2s[k * NC + 2 * j2];
            ob += hv * w2s[k * NC + 2 * j2 + 1];
        }
        int node2 = blockIdx.x * 32 + n2;
        float d2 = dinv[node2];
        hs2b[(node2 << 2) + j2] = bf16pair(oa * d2, ob * d2);
    }
}

// ---------------- layer 2 aggregate (LDS-staged edges) + log_softmax ----------------
// 256 threads = 64 nodes x 4 lanes
__global__ __launch_bounds__(256) void k_l2(const uint2* __restrict__ row_se,
                                            const unsigned* __restrict__ srcsort,
                                            const unsigned* __restrict__ hs2b,
                                            const float* __restrict__ dinv,
                                            const float* __restrict__ b2,
                                            float* __restrict__ out) {
    __shared__ __attribute__((aligned(16))) unsigned estg[LCH2 + 8];
    __shared__ unsigned sh_lo, sh_hi;
    int t = threadIdx.x;
    int g = t >> 2;          // node in block 0..63
    int c2 = t & 3;          // uint index (2 channels)
    int n0 = blockIdx.x * 64;
    if (n0 >= NN) return;    // BUGFIX R12: last block would read past row_se (uniform exit, pre-barrier)
    int n = n0 + g;
    uint2 se = (n < NN) ? row_se[n] : uint2{0u, 0u};
    if (t == 0)   sh_lo = row_se[n0].x;
    if (t == 255) { int nl = n0 + 63; if (nl >= NN) nl = NN - 1; sh_hi = row_se[nl].y; }
    __syncthreads();
    unsigned lo = sh_lo, hi = sh_hi;
    float a0 = 0.f, a1 = 0.f;
    for (unsigned cb = lo; cb < hi; cb += LCH2) {
        unsigned cnt = hi - cb; if (cnt > LCH2) cnt = LCH2;
        unsigned cb0 = cb & ~3u;
        unsigned tot = (cb - cb0) + cnt;
        unsigned n4 = (tot + 3) >> 2;
        for (unsigned i = t; i < n4; i += 256)
            *reinterpret_cast<uint4*>(&estg[i << 2]) =
                *reinterpret_cast<const uint4*>(&srcsort[cb0 + (i << 2)]);
        __syncthreads();
        unsigned es = se.x > cb ? se.x : cb;
        unsigned ee = se.y < cb + cnt ? se.y : cb + cnt;
        unsigned e = es;
        for (; e + 3 < ee; e += 4) {
            int s0 = estg[e - cb0];
            int s1 = estg[e + 1 - cb0];
            int s2 = estg[e + 2 - cb0];
            int s3 = estg[e + 3 - cb0];
            unsigned v0 = hs2b[(s0 << 2) + c2];
            unsigned v1 = hs2b[(s1 << 2) + c2];
            unsigned v2 = hs2b[(s2 << 2) + c2];
            unsigned v3 = hs2b[(s3 << 2) + c2];
            a0 += __uint_as_float(v0 << 16) + __uint_as_float(v1 << 16)
                + __uint_as_float(v2 << 16) + __uint_as_float(v3 << 16);
            a1 += __uint_as_float(v0 & 0xffff0000u) + __uint_as_float(v1 & 0xffff0000u)
                + __uint_as_float(v2 & 0xffff0000u) + __uint_as_float(v3 & 0xffff0000u);
        }
        for (; e < ee; ++e) {
            unsigned v = hs2b[((int)estg[e - cb0] << 2) + c2];
            a0 += __uint_as_float(v << 16);
            a1 += __uint_as_float(v & 0xffff0000u);
        }
        __syncthreads();
    }
    if (n >= NN) return;
    {   // self-loop
        unsigned v = hs2b[(n << 2) + c2];
        a0 += __uint_as_float(v << 16);
        a1 += __uint_as_float(v & 0xffff0000u);
    }
    float di = dinv[n];
    int c = c2 * 2;
    float v0 = a0 * di + b2[c];
    float v1 = a1 * di + b2[c + 1];
    float m = fmaxf(v0, v1);
    m = fmaxf(m, __shfl_xor(m, 1, 4));
    m = fmaxf(m, __shfl_xor(m, 2, 4));
    float s = expf(v0 - m) + expf(v1 - m);
    s += __shfl_xor(s, 1, 4);
    s += __shfl_xor(s, 2, 4);
    float ls = logf(s);
    float2 o = {v0 - m - ls, v1 - m - ls};
    *reinterpret_cast<float2*>(&out[(n << 3) + c]) = o;
}

extern "C" void kernel_launch(void* const* d_in, const int* in_sizes, int n_in,
                              void* d_out, int out_size, void* d_ws, size_t ws_size,
                              hipStream_t stream) {
    const float* x   = (const float*)d_in[0];
    const int*   ei  = (const int*)d_in[1];
    const float* W1  = (const float*)d_in[2];
    const float* b1  = (const float*)d_in[3];
    const float* W2  = (const float*)d_in[4];
    const float* b2  = (const float*)d_in[5];
    float* out = (float*)d_out;

    const int* row = ei;
    const int* col = ei + EE;

    // ws layout (4-byte units)
    float*    ws      = (float*)d_ws;
    float*    dinv    = ws;                                    // NN
    unsigned* hs1b    = (unsigned*)(dinv + NN);                // NN*8 (bf16 x16)
    unsigned* hs2b    = hs1b + (size_t)NN * 8;                 // NN*4 (bf16 x8)
    uint2*    row_se  = (uint2*)(hs2b + (size_t)NN * 4);       // NN uint2
    unsigned* cursor  = (unsigned*)(row_se + NN);              // NBUK
    unsigned* bins_pk = cursor + NBUK + 1;                     // NBUK*CAP slab (16B-aligned)
    unsigned* srcsort = bins_pk + (size_t)NBUK * CAP;          // NBUK*CAP slab

    hipMemsetAsync(cursor, 0, NBUK * sizeof(unsigned), stream);
    k_binscatter  <<<NBLK, 1024, 0, stream>>>(row, col, cursor, bins_pk);
    k_build       <<<NBUK, 1024, 0, stream>>>(bins_pk, cursor, row_se, dinv, srcsort);
    k_gemm1       <<<(NN + 63) / 64, 256, 0, stream>>>(x, W1, dinv, hs1b);
    k_l1          <<<NN / 32, 256, 0, stream>>>(row_se, srcsort, hs1b, dinv, W2, b1, hs2b);
    k_l2          <<<(NN + 63) / 64, 256, 0, stream>>>(row_se, srcsort, hs2b, dinv, b2, out);
}